// Round 13
// baseline (407.906 us; speedup 1.0000x reference)
//
#include <hip/hip_runtime.h>

#define C 64

typedef float f4 __attribute__((ext_vector_type(4)));

// ---------------------------------------------------------------------------
// Bucket CSR, 4 dispatches (ovfdiv folded away):
//  1. zero:   cnt[n_vox], spill_n = 0
//  2. build:  r = atomicAdd(&cnt[v],1); r<K ? bucket[v*K+r]=pid : spill
//  3. fused:  16 thr/voxel in voxel order; lane-parallel bucket load + shfl;
//             8-wide chunked row prefetch (rows issued back-to-back before
//             compute); v_new = acc/max(n,1) ALWAYS (partial sum pre-divided
//             for overflow voxels -> no separate divide pass)
//  4. spill:  rare points past K add f/cnt[v] (pre-divided) into v_new
// ---------------------------------------------------------------------------

__global__ __launch_bounds__(256) void zero_kernel(int* __restrict__ p, int n)
{
    int i = blockIdx.x * blockDim.x + threadIdx.x;
    if (i < n) p[i] = 0;
}

__global__ __launch_bounds__(256) void build_kernel(
    const int* __restrict__ p2v, int* __restrict__ cnt,
    int* __restrict__ bucket, int* __restrict__ spill, int* __restrict__ spill_n,
    int n_pts, int K)
{
    int i = blockIdx.x * blockDim.x + threadIdx.x;
    if (i >= n_pts) return;
    const int v = p2v[i];
    const int r = atomicAdd(&cnt[v], 1);
    if (r < K) {
        bucket[(size_t)v * K + r] = i;
    } else {
        int s = atomicAdd(spill_n, 1);
        spill[s] = i;
    }
}

__global__ __launch_bounds__(256) void fused_kernel(
    const float* __restrict__ p_feats, const float* __restrict__ v_feats,
    const float* __restrict__ Wp, const float* __restrict__ bp,
    const float* __restrict__ Wv, const float* __restrict__ bv,
    const int* __restrict__ cnt, const int* __restrict__ bucket,
    float* __restrict__ fuse_out, float* __restrict__ v_new, int n_vox, int K)
{
    const int gid = blockIdx.x * blockDim.x + threadIdx.x;
    const int v = gid >> 4;          // 16 threads per voxel, voxel order = id
    const int t = gid & 15;          // 4 channels per thread
    if (v >= n_vox) return;

    const f4* Wp4 = (const f4*)Wp;
    const f4* Wv4 = (const f4*)Wv;
    const f4 wpA = Wp4[2 * t], wpB = Wp4[2 * t + 1];
    const f4 wvA = Wv4[2 * t], wvB = Wv4[2 * t + 1];
    const float bias0 = bp[0] + bv[0];
    const float bias1 = bp[1] + bv[1];

    const f4 vf = *(const f4*)(v_feats + (size_t)v * C + t * 4);

    // v-side logit contribution (computed once per voxel)
    float lv0 = vf.x * wvA.x + vf.y * wvA.z + vf.z * wvB.x + vf.w * wvB.z;
    float lv1 = vf.x * wvA.y + vf.y * wvA.w + vf.z * wvB.y + vf.w * wvB.w;
    #pragma unroll
    for (int m = 1; m < 16; m <<= 1) {
        lv0 += __shfl_xor(lv0, m);
        lv1 += __shfl_xor(lv1, m);
    }
    lv0 += bias0;
    lv1 += bias1;

    const int n = cnt[v];
    const int m = min(n, K);
    const size_t b0 = (size_t)v * K;
    f4 acc = (f4){0.f, 0.f, 0.f, 0.f};

    // lane-parallel bucket load: slot t's pid (one coalesced load per group)
    int pid_t = 0;
    if (t < m) pid_t = bucket[b0 + t];

    // chunks of 8: issue all rows of the chunk back-to-back before compute.
    // (P(count>8) ~ 7% => one latency round for 93% of voxels)
#define LD(j, q, a)                                                             \
    if ((j) < rem) {                                                            \
        q = __shfl(pid_t, base + (j), 16);                                      \
        a = __builtin_nontemporal_load(                                         \
            (const f4*)(p_feats + (size_t)q * C + t * 4));                      \
    }

#define PROC(j, q, a)                                                           \
    if ((j) < rem) {                                                            \
        float l0 = a.x * wpA.x + a.y * wpA.z + a.z * wpB.x + a.w * wpB.z;       \
        float l1 = a.x * wpA.y + a.y * wpA.w + a.z * wpB.y + a.w * wpB.w;       \
        _Pragma("unroll")                                                       \
        for (int mm = 1; mm < 16; mm <<= 1) {                                   \
            l0 += __shfl_xor(l0, mm);                                           \
            l1 += __shfl_xor(l1, mm);                                           \
        }                                                                       \
        l0 += lv0;                                                              \
        l1 += lv1;                                                              \
        const float mx = fmaxf(l0, l1);                                         \
        const float e0 = __expf(l0 - mx), e1 = __expf(l1 - mx);                 \
        const float w0 = e0 / (e0 + e1);                                        \
        const float w1 = 1.0f - w0;                                             \
        f4 f;                                                                   \
        f.x = a.x * w0 + vf.x * w1;                                             \
        f.y = a.y * w0 + vf.y * w1;                                             \
        f.z = a.z * w0 + vf.z * w1;                                             \
        f.w = a.w * w0 + vf.w * w1;                                             \
        __builtin_nontemporal_store(f, (f4*)(fuse_out + (size_t)q * C + t * 4));\
        acc.x += f.x; acc.y += f.y; acc.z += f.z; acc.w += f.w;                 \
    }

    int base = 0;
    while (base < m) {
        const int rem = m - base;
        int q0 = 0, q1 = 0, q2 = 0, q3 = 0, q4 = 0, q5 = 0, q6 = 0, q7 = 0;
        f4 a0, a1, a2, a3, a4, a5, a6, a7;
        LD(0, q0, a0) LD(1, q1, a1) LD(2, q2, a2) LD(3, q3, a3)
        LD(4, q4, a4) LD(5, q5, a5) LD(6, q6, a6) LD(7, q7, a7)
        PROC(0, q0, a0) PROC(1, q1, a1) PROC(2, q2, a2) PROC(3, q3, a3)
        PROC(4, q4, a4) PROC(5, q5, a5) PROC(6, q6, a6) PROC(7, q7, a7)
        base += 8;
    }
#undef LD
#undef PROC

    // always pre-divided by the FULL count (overflow voxels get the rest,
    // also pre-divided, from spill_kernel; no separate divide pass needed)
    const float inv = 1.0f / (float)max(n, 1);
    f4 r;
    r.x = acc.x * inv; r.y = acc.y * inv; r.z = acc.z * inv; r.w = acc.w * inv;
    *(f4*)(v_new + (size_t)v * C + t * 4) = r;
}

__global__ __launch_bounds__(256) void spill_kernel(
    const float* __restrict__ p_feats, const float* __restrict__ v_feats,
    const float* __restrict__ Wp, const float* __restrict__ bp,
    const float* __restrict__ Wv, const float* __restrict__ bv,
    const int* __restrict__ p2v, const int* __restrict__ spill,
    const int* __restrict__ spill_n, const int* __restrict__ cnt,
    float* __restrict__ fuse_out, float* __restrict__ v_new)
{
    const int sn = *spill_n;
    const int total = sn * 16;
    const int T_all = gridDim.x * blockDim.x;
    const int gtid = blockIdx.x * blockDim.x + threadIdx.x;

    for (int slot = gtid; slot < total; slot += T_all) {
        const int j = slot >> 4;
        const int t = slot & 15;

        const int pid = spill[j];
        const int v = p2v[pid];

        const f4* Wp4 = (const f4*)Wp;
        const f4* Wv4 = (const f4*)Wv;
        const f4 wpA = Wp4[2 * t], wpB = Wp4[2 * t + 1];
        const f4 wvA = Wv4[2 * t], wvB = Wv4[2 * t + 1];

        const f4 vf = *(const f4*)(v_feats + (size_t)v * C + t * 4);
        const f4 pf = *(const f4*)(p_feats + (size_t)pid * C + t * 4);

        float l0 = pf.x * wpA.x + pf.y * wpA.z + pf.z * wpB.x + pf.w * wpB.z
                 + vf.x * wvA.x + vf.y * wvA.z + vf.z * wvB.x + vf.w * wvB.z;
        float l1 = pf.x * wpA.y + pf.y * wpA.w + pf.z * wpB.y + pf.w * wpB.w
                 + vf.x * wvA.y + vf.y * wvA.w + vf.z * wvB.y + vf.w * wvB.w;
        #pragma unroll
        for (int m = 1; m < 16; m <<= 1) {
            l0 += __shfl_xor(l0, m);
            l1 += __shfl_xor(l1, m);
        }
        l0 += bp[0] + bv[0];
        l1 += bp[1] + bv[1];

        const float mx = fmaxf(l0, l1);
        const float e0 = __expf(l0 - mx), e1 = __expf(l1 - mx);
        const float w0 = e0 / (e0 + e1);
        const float w1 = 1.0f - w0;

        f4 f;
        f.x = pf.x * w0 + vf.x * w1;
        f.y = pf.y * w0 + vf.y * w1;
        f.z = pf.z * w0 + vf.z * w1;
        f.w = pf.w * w0 + vf.w * w1;

        *(f4*)(fuse_out + (size_t)pid * C + t * 4) = f;

        // pre-divided contribution (fused wrote partial/n for this voxel)
        const float inv = 1.0f / (float)cnt[v];
        float* s = v_new + (size_t)v * C + t * 4;
        atomicAdd(s + 0, f.x * inv);
        atomicAdd(s + 1, f.y * inv);
        atomicAdd(s + 2, f.z * inv);
        atomicAdd(s + 3, f.w * inv);
    }
}

extern "C" void kernel_launch(void* const* d_in, const int* in_sizes, int n_in,
                              void* d_out, int out_size, void* d_ws, size_t ws_size,
                              hipStream_t stream) {
    const float* p_feats = (const float*)d_in[0];
    const float* v_feats = (const float*)d_in[1];
    const float* Wp = (const float*)d_in[2];
    const float* bp = (const float*)d_in[3];
    const float* Wv = (const float*)d_in[4];
    const float* bv = (const float*)d_in[5];
    const int* p2v = (const int*)d_in[6];

    const int n_pts = in_sizes[0] / C;
    const int n_vox = in_sizes[1] / C;

    float* fuse_out = (float*)d_out;
    float* v_new = fuse_out + (size_t)n_pts * C;

    // ws layout (ints): cnt[n_vox] | spill_n | pad->16
    //                 | bucket[n_vox*K] | spill[n_pts]
    // strictly within the R8-proven footprint.
    const size_t ws_ints = ws_size / sizeof(int);
    const size_t fixed = (size_t)n_vox + 16 + (size_t)n_pts;
    long long avail = (long long)ws_ints - (long long)fixed;
    int K = 16;
    if (avail < (long long)n_vox * K) K = (int)(avail / (long long)n_vox);
    if (K < 1) K = 1;

    int* cnt = (int*)d_ws;
    int* spill_n = cnt + n_vox;
    int* bucket = cnt + n_vox + 16;
    int* spill = bucket + (size_t)n_vox * K;

    const int T = 256;

    zero_kernel<<<(n_vox + 1 + T - 1) / T, T, 0, stream>>>(cnt, n_vox + 1);
    build_kernel<<<(n_pts + T - 1) / T, T, 0, stream>>>(
        p2v, cnt, bucket, spill, spill_n, n_pts, K);
    fused_kernel<<<((size_t)n_vox * 16 + T - 1) / T, T, 0, stream>>>(
        p_feats, v_feats, Wp, bp, Wv, bv, cnt, bucket,
        fuse_out, v_new, n_vox, K);
    spill_kernel<<<32, T, 0, stream>>>(
        p_feats, v_feats, Wp, bp, Wv, bv, p2v, spill, spill_n, cnt,
        fuse_out, v_new);
}